// Round 3
// baseline (304.318 us; speedup 1.0000x reference)
//
#include <hip/hip_runtime.h>
#include <hip/hip_bf16.h>
#include <stdint.h>

#define SEQ    2048
#define HIDDEN 1024
#define NH     16
#define HD     64

typedef __bf16 bf16x8 __attribute__((ext_vector_type(8)));
typedef float  f32x4  __attribute__((ext_vector_type(4)));

typedef __attribute__((address_space(1))) void* as1vp;
typedef __attribute__((address_space(3))) void* as3vp;

__device__ __forceinline__ void gload_lds16(const void* g, void* l) {
  // global -> LDS direct copy, 16B/lane. LDS dest = wave-uniform base + lane*16.
  __builtin_amdgcn_global_load_lds((as1vp)(void*)g, (as3vp)l, 16, 0, 0);
}

__device__ __forceinline__ uint16_t f2bf(float f) {
  uint32_t x;
  __builtin_memcpy(&x, &f, 4);
  x += 0x7FFFu + ((x >> 16) & 1u);   // round-to-nearest-even
  return (uint16_t)(x >> 16);
}

// ---------------------------------------------------------------------------
// Convert Q/K/V fp32 -> bf16 (tensor selected by blockIdx.y).
// 4,194,304 elems each = 2048 blocks x 256 thr x 8 elems exactly.
// ---------------------------------------------------------------------------
__global__ __launch_bounds__(256) void k_cvt(
    const float* __restrict__ Q, const float* __restrict__ K, const float* __restrict__ V,
    uint16_t* __restrict__ Qb, uint16_t* __restrict__ Kb, uint16_t* __restrict__ Vb) {
  const float* src = (blockIdx.y == 0) ? Q : (blockIdx.y == 1) ? K : V;
  uint16_t*    dst = (blockIdx.y == 0) ? Qb : (blockIdx.y == 1) ? Kb : Vb;
  const int i = (blockIdx.x * 256 + threadIdx.x) * 8;
  float4 v0 = *(const float4*)(src + i);
  float4 v1 = *(const float4*)(src + i + 4);
  uint16_t tmp[8];
  tmp[0] = f2bf(v0.x); tmp[1] = f2bf(v0.y); tmp[2] = f2bf(v0.z); tmp[3] = f2bf(v0.w);
  tmp[4] = f2bf(v1.x); tmp[5] = f2bf(v1.y); tmp[6] = f2bf(v1.z); tmp[7] = f2bf(v1.w);
  __builtin_memcpy(dst + i, tmp, 16);
}

// ---------------------------------------------------------------------------
// Transpose W fp32 [K=1024][N=1024] -> WT bf16 [N][K] (matrix by blockIdx.y)
// ---------------------------------------------------------------------------
__global__ __launch_bounds__(256) void k_transpose(
    const float* __restrict__ W0, const float* __restrict__ W1, const float* __restrict__ W2,
    uint16_t* __restrict__ T0, uint16_t* __restrict__ T1, uint16_t* __restrict__ T2) {
  __shared__ uint16_t t[64][65];
  const float* W = (blockIdx.y == 0) ? W0 : (blockIdx.y == 1) ? W1 : W2;
  uint16_t*    T = (blockIdx.y == 0) ? T0 : (blockIdx.y == 1) ? T1 : T2;
  const int bx = blockIdx.x & 15, by = blockIdx.x >> 4;
  const int tx = threadIdx.x & 63, ty = threadIdx.x >> 6;
  for (int i = ty; i < 64; i += 4)
    t[i][tx] = f2bf(W[(by * 64 + i) * HIDDEN + bx * 64 + tx]);
  __syncthreads();
  for (int i = ty; i < 64; i += 4)
    T[(bx * 64 + i) * HIDDEN + by * 64 + tx] = t[tx][i];
}

// ---------------------------------------------------------------------------
// QKV projection GEMM: out = X @ W + b  (B^T layout via WT, bf16 in / bf16 out)
// 128x128 tile, BK=64, 4 waves each 64x64, mfma_f32_16x16x32_bf16.
// Linear LDS (m97 pattern).  bias is fp32.
// mode (blockIdx.z): 0=q (scaled 0.125, [b,h,s,d]) 1=k ([b,h,s,d]) 2=v ([b,h,d,s])
// ---------------------------------------------------------------------------
__global__ __launch_bounds__(256) void k_qkv_gemm(
    const uint16_t* __restrict__ Qb, const uint16_t* __restrict__ Kb, const uint16_t* __restrict__ Vb,
    const uint16_t* __restrict__ WTq, const uint16_t* __restrict__ WTk, const uint16_t* __restrict__ WTv,
    const float* __restrict__ Bq, const float* __restrict__ Bk, const float* __restrict__ Bv,
    uint16_t* __restrict__ q_ws, uint16_t* __restrict__ k_ws, uint16_t* __restrict__ v_ws) {
  const int mode = blockIdx.z;
  const uint16_t* X   = (mode == 0) ? Qb : (mode == 1) ? Kb : Vb;
  const uint16_t* WT  = (mode == 0) ? WTq : (mode == 1) ? WTk : WTv;
  const float*    bia = (mode == 0) ? Bq  : (mode == 1) ? Bk  : Bv;

  __shared__ uint16_t As[128 * 64];
  __shared__ uint16_t Bs[128 * 64];
  char* AsB = (char*)As;
  char* BsB = (char*)Bs;

  const int tid  = threadIdx.x;
  const int lane = tid & 63;
  const int w    = tid >> 6;
  const int wr   = w >> 1, wc = w & 1;
  const int m0   = blockIdx.y * 128;
  const int n0   = blockIdx.x * 128;

  const int lrow = lane >> 3;              // row within the 8-row group of one load
  const int lcol = (lane & 7) * 16;        // byte column within the 128B row

  f32x4 acc[4][4];
  const f32x4 zero = {0.f, 0.f, 0.f, 0.f};
#pragma unroll
  for (int i = 0; i < 4; ++i)
#pragma unroll
    for (int j = 0; j < 4; ++j) acc[i][j] = zero;

  const char* Ab = (const char*)X;
  const char* Bb = (const char*)WT;

  for (int kt = 0; kt < 16; ++kt) {
    __syncthreads();
    const int kbyte = kt * 128;
#pragma unroll
    for (int i = 0; i < 4; ++i) {
      const int r = w * 32 + i * 8;  // 8 rows per instruction (64 lanes * 16B)
      gload_lds16(Ab + (size_t)(m0 + r + lrow) * (HIDDEN * 2) + kbyte + lcol, AsB + r * 128);
      gload_lds16(Bb + (size_t)(n0 + r + lrow) * (HIDDEN * 2) + kbyte + lcol, BsB + r * 128);
    }
    __syncthreads();
#pragma unroll
    for (int kc = 0; kc < 2; ++kc) {
      const int chunk = kc * 64 + (lane >> 4) * 16;
      bf16x8 a[4], b[4];
#pragma unroll
      for (int f = 0; f < 4; ++f) {
        const int ra = wr * 64 + f * 16 + (lane & 15);
        a[f] = *(const bf16x8*)(AsB + ra * 128 + chunk);
        const int rb = wc * 64 + f * 16 + (lane & 15);
        b[f] = *(const bf16x8*)(BsB + rb * 128 + chunk);
      }
#pragma unroll
      for (int fm = 0; fm < 4; ++fm)
#pragma unroll
        for (int fn = 0; fn < 4; ++fn)
          acc[fm][fn] = __builtin_amdgcn_mfma_f32_16x16x32_bf16(a[fm], b[fn], acc[fm][fn], 0, 0, 0);
    }
  }

  // epilogue: bias (+ q-scale), scatter to head-major bf16 layouts
  float bfrag[4];
#pragma unroll
  for (int fn = 0; fn < 4; ++fn)
    bfrag[fn] = bia[n0 + wc * 64 + fn * 16 + (lane & 15)];

#pragma unroll
  for (int fm = 0; fm < 4; ++fm) {
    const int mrow0 = m0 + wr * 64 + fm * 16 + (lane >> 4) * 4;  // 4-row run, same batch
    const int b0 = mrow0 >> 11;
    const int s0 = mrow0 & (SEQ - 1);
#pragma unroll
    for (int fn = 0; fn < 4; ++fn) {
      const int n = n0 + wc * 64 + fn * 16 + (lane & 15);
      const int h = n >> 6, d = n & 63;
      if (mode == 2) {
        uint16_t tmp[4];
#pragma unroll
        for (int j = 0; j < 4; ++j) tmp[j] = f2bf(acc[fm][fn][j] + bfrag[fn]);
        __builtin_memcpy(v_ws + ((size_t)(b0 * NH + h) * HD + d) * SEQ + s0, tmp, 8);
      } else {
        const float sc = (mode == 0) ? 0.125f : 1.0f;  // fold 1/sqrt(64) into q
        uint16_t* o = (mode == 0) ? q_ws : k_ws;
#pragma unroll
        for (int j = 0; j < 4; ++j)
          o[((size_t)(b0 * NH + h) * SEQ + (s0 + j)) * HD + d] =
              f2bf((acc[fm][fn][j] + bfrag[fn]) * sc);
      }
    }
  }
}

// ---------------------------------------------------------------------------
// Flash attention: grid (32 q-tiles, 32 bh), 4 waves x 16 q-rows, KV tile = 64.
// K/V fragments read DIRECTLY from global (L2-resident; rows are contiguous
// 16B fragments in both layouts). Only P round-trips through per-wave LDS.
// score = (q*0.125) . k + mask*0.125 ; online softmax; O = sum(P v)/l
// mask is fp32, output is fp32.
// ---------------------------------------------------------------------------
__global__ __launch_bounds__(256) void k_attn(
    const uint16_t* __restrict__ q_ws, const uint16_t* __restrict__ k_ws,
    const uint16_t* __restrict__ v_ws, const float* __restrict__ mask,
    float* __restrict__ out) {
  __shared__ uint16_t Pt[4][16 * 64];   // per-wave P (bf16), swizzled rows

  const int tid = threadIdx.x, lane = tid & 63, w = tid >> 6;
  const int bh = blockIdx.y;
  const int b  = bh >> 4;
  const int h  = bh & 15;
  const int q0 = blockIdx.x * 64 + w * 16;

  char* PtB = (char*)(&Pt[w][0]);
  const char* kb = (const char*)k_ws;
  const char* vb = (const char*)v_ws;

  // Q fragments in registers for the whole kernel (A operand of QK^T)
  bf16x8 qf0, qf1;
  {
    const char* qb = (const char*)q_ws;
    const size_t rowb = ((size_t)bh * SEQ + q0 + (lane & 15)) * (HD * 2);
    qf0 = *(const bf16x8*)(qb + rowb + (lane >> 4) * 16);
    qf1 = *(const bf16x8*)(qb + rowb + 64 + (lane >> 4) * 16);
  }

  const f32x4 zero = {0.f, 0.f, 0.f, 0.f};
  f32x4 Oacc[4];
#pragma unroll
  for (int i = 0; i < 4; ++i) Oacc[i] = zero;
  float mrun[4], lrun[4];
#pragma unroll
  for (int j = 0; j < 4; ++j) { mrun[j] = -1e30f; lrun[j] = 0.f; }

  for (int kt = 0; kt < 32; ++kt) {
    // ---- QK^T: B fragments straight from k_ws rows ----
    f32x4 sv[4];
#pragma unroll
    for (int g = 0; g < 4; ++g) {
      const char* krow = kb + ((size_t)bh * SEQ + kt * 64 + g * 16 + (lane & 15)) * (HD * 2);
      bf16x8 kf0 = *(const bf16x8*)(krow + (lane >> 4) * 16);
      bf16x8 kf1 = *(const bf16x8*)(krow + 64 + (lane >> 4) * 16);
      f32x4 t = __builtin_amdgcn_mfma_f32_16x16x32_bf16(qf0, kf0, zero, 0, 0, 0);
      sv[g]   = __builtin_amdgcn_mfma_f32_16x16x32_bf16(qf1, kf1, t, 0, 0, 0);
    }
#pragma unroll
    for (int g = 0; g < 4; ++g) {
      const float mv = mask[b * SEQ + kt * 64 + g * 16 + (lane & 15)] * 0.125f;
#pragma unroll
      for (int j = 0; j < 4; ++j) sv[g][j] += mv;
    }

    // ---- online softmax (row reductions across the 16-lane group) ----
    float mnew[4], esc[4];
#pragma unroll
    for (int j = 0; j < 4; ++j) {
      float v = fmaxf(fmaxf(sv[0][j], sv[1][j]), fmaxf(sv[2][j], sv[3][j]));
#pragma unroll
      for (int mk = 1; mk < 16; mk <<= 1) v = fmaxf(v, __shfl_xor(v, mk, 64));
      mnew[j] = fmaxf(mrun[j], v);
      esc[j]  = __expf(mrun[j] - mnew[j]);
      mrun[j] = mnew[j];
    }
    float tsum[4] = {0.f, 0.f, 0.f, 0.f};
#pragma unroll
    for (int g = 0; g < 4; ++g)
#pragma unroll
      for (int j = 0; j < 4; ++j) {
        const float p = __expf(sv[g][j] - mnew[j]);
        sv[g][j] = p;
        tsum[j] += p;
      }
#pragma unroll
    for (int j = 0; j < 4; ++j) {
      float v = tsum[j];
#pragma unroll
      for (int mk = 1; mk < 16; mk <<= 1) v += __shfl_xor(v, mk, 64);
      lrun[j] = lrun[j] * esc[j] + v;
    }
#pragma unroll
    for (int dg = 0; dg < 4; ++dg)
#pragma unroll
      for (int j = 0; j < 4; ++j) Oacc[dg][j] *= esc[j];

    // ---- P -> per-wave LDS (C-layout -> A-fragment layout), swizzled ----
#pragma unroll
    for (int g = 0; g < 4; ++g)
#pragma unroll
      for (int j = 0; j < 4; ++j) {
        const int row = (lane >> 4) * 4 + j;
        const int col = g * 16 + (lane & 15);
        ((uint16_t*)PtB)[row * 64 + (col ^ ((row & 7) << 3))] = f2bf(sv[g][j]);
      }

    // ---- PV: A = P from LDS, B = V fragments straight from v_ws [bh][d][s] ----
#pragma unroll
    for (int kc = 0; kc < 2; ++kc) {
      const int chunk = kc * 64 + (lane >> 4) * 16;
      const int pr = lane & 15;
      bf16x8 pa = *(const bf16x8*)(PtB + pr * 128 + (chunk ^ ((pr & 7) << 4)));
#pragma unroll
      for (int dg = 0; dg < 4; ++dg) {
        const char* vrow = vb + ((size_t)bh * HD + dg * 16 + (lane & 15)) * (SEQ * 2) + kt * 128;
        bf16x8 vf = *(const bf16x8*)(vrow + chunk);
        Oacc[dg] = __builtin_amdgcn_mfma_f32_16x16x32_bf16(pa, vf, Oacc[dg], 0, 0, 0);
      }
    }
  }

  // epilogue: normalize and write out[b, q, h*64+d] (fp32)
#pragma unroll
  for (int dg = 0; dg < 4; ++dg)
#pragma unroll
    for (int j = 0; j < 4; ++j) {
      const int q = q0 + (lane >> 4) * 4 + j;
      const int d = dg * 16 + (lane & 15);
      out[(size_t)(b * SEQ + q) * HIDDEN + h * HD + d] = Oacc[dg][j] / lrun[j];
    }
}

// ---------------------------------------------------------------------------
extern "C" void kernel_launch(void* const* d_in, const int* in_sizes, int n_in,
                              void* d_out, int out_size, void* d_ws, size_t ws_size,
                              hipStream_t stream) {
  (void)in_sizes; (void)n_in; (void)out_size; (void)ws_size;
  const float* Q    = (const float*)d_in[0];
  const float* K    = (const float*)d_in[1];
  const float* V    = (const float*)d_in[2];
  const float* mask = (const float*)d_in[3];
  const float* Wq   = (const float*)d_in[4];
  const float* bq   = (const float*)d_in[5];
  const float* Wk   = (const float*)d_in[6];
  const float* bk   = (const float*)d_in[7];
  const float* Wv   = (const float*)d_in[8];
  const float* bv   = (const float*)d_in[9];

  uint16_t* ws   = (uint16_t*)d_ws;
  uint16_t* wt_q = ws;                           // 3 x 2MB transposed bf16 weights
  uint16_t* wt_k = wt_q + HIDDEN * HIDDEN;
  uint16_t* wt_v = wt_k + HIDDEN * HIDDEN;
  const size_t qkv = (size_t)2 * SEQ * HIDDEN;   // 4M elems each
  uint16_t* Qb   = wt_v + HIDDEN * HIDDEN;       // 3 x 8MB bf16 inputs
  uint16_t* Kb   = Qb + qkv;
  uint16_t* Vb   = Kb + qkv;
  uint16_t* q_ws = Vb + qkv;                     // 3 x 8MB bf16 projections
  uint16_t* k_ws = q_ws + qkv;
  uint16_t* v_ws = k_ws + qkv;
  // total ws use: 54 MB

  k_cvt<<<dim3(2048, 3), 256, 0, stream>>>(Q, K, V, Qb, Kb, Vb);
  k_transpose<<<dim3(256, 3), 256, 0, stream>>>(Wq, Wk, Wv, wt_q, wt_k, wt_v);
  k_qkv_gemm<<<dim3(HIDDEN / 128, (2 * SEQ) / 128, 3), 256, 0, stream>>>(
      Qb, Kb, Vb, wt_q, wt_k, wt_v, bq, bk, bv, q_ws, k_ws, v_ws);
  k_attn<<<dim3(SEQ / 64, 2 * NH), 256, 0, stream>>>(q_ws, k_ws, v_ws, mask,
                                                     (float*)d_out);
}